// Round 10
// baseline (420.105 us; speedup 1.0000x reference)
//
#include <hip/hip_runtime.h>
#include <float.h>
#include <math.h>

// Problem constants (from reference setup_inputs)
#define B_   32
#define D_   128
#define T_   2048
#define K_   2048
#define N_   (B_ * T_)      // 65536
#define GRID_A 512          // argmin grid: 64 KB LDS -> exactly 2 blocks/CU x 256 CU
#define GRID_T 512          // tail grid: trivially all-resident

typedef _Float16 f16;
typedef f16   f16x8 __attribute__((ext_vector_type(8)));
typedef f16   f16x4 __attribute__((ext_vector_type(4)));
typedef f16   f16x2 __attribute__((ext_vector_type(2)));
typedef float f32x4 __attribute__((ext_vector_type(4)));

// async global->LDS, 16 B per lane, LDS dst = wave-uniform base + lane*16
__device__ __forceinline__ void load_lds16(const void* g, void* l) {
    __builtin_amdgcn_global_load_lds(
        (const __attribute__((address_space(1))) unsigned int*)g,
        (__attribute__((address_space(3))) unsigned int*)l, 16, 0, 0);
}

// Software grid barrier (what cg::grid_group::sync does, minus the launch API
// that crashed the graph-capture harness in R9). SAFE ONLY because the grid
// is fully resident (grid <= capacity): argmin = 512 = 2/CU x 256 CU exact;
// tail = 512 small blocks. Stores -> threadfence -> release-add; acquire-load
// spin gives cross-XCD visibility (G16 device-scope discipline).
__device__ __forceinline__ void grid_barrier(int* bar, int expected) {
    __syncthreads();
    if (threadIdx.x == 0) {
        __threadfence();
        __hip_atomic_fetch_add(bar, 1, __ATOMIC_ACQ_REL, __HIP_MEMORY_SCOPE_AGENT);
        while (__hip_atomic_load(bar, __ATOMIC_ACQUIRE,
                                 __HIP_MEMORY_SCOPE_AGENT) < expected)
            __builtin_amdgcn_s_sleep(1);
    }
    __syncthreads();
}

// ---------------------------------------------------------------------------
// MFMA distance-argmin MEGA-KERNEL (R8-proven body + fused eprep).
//   eprep slice (this block's 4 codes) + z-prologue run BEFORE the software
//   grid barrier; eh/el/hn are read only after it. Everything from the
//   B tile-0 stage onward is byte-identical to R8's passing kernel.
// ---------------------------------------------------------------------------
__global__ __launch_bounds__(256, 2)
void argmin_mfma(const float* __restrict__ z,
                 f16* __restrict__ eh, f16* __restrict__ el,
                 float* __restrict__ hn, const float* __restrict__ emb,
                 float* __restrict__ zt, float* __restrict__ out0,
                 int* __restrict__ idx, int* __restrict__ cnt, int* __restrict__ pos,
                 int* __restrict__ offs, int* __restrict__ ticket,
                 float* __restrict__ s_loss, float* __restrict__ scalars,
                 float* __restrict__ sum_new, int* __restrict__ bars) {
    __shared__ __align__(16) f16 BS[2][2][64 * 128];   // 64 KB, multi-purpose

    const int tid = threadIdx.x;
    const int w   = tid >> 6;            // wave 0..3
    const int l   = tid & 63;
    const int wm  = w >> 1;              // M-half: rows wm*64..
    const int wn  = w & 1;               // N-half: codes wn*32.. of 64-code tile
    const int n0  = blockIdx.x * 128;    // 512 blocks
    const int b   = n0 >> 11;            // n0 / 2048
    const int t0  = n0 & 2047;
    const int c15 = l & 15;
    const int q   = l >> 4;

    const float* zbase = z    + (size_t)b * D_ * T_ + t0;
    float*       obase = out0 + (size_t)b * D_ * T_ + t0;

    // ================= FUSED EPREP: this block's 4 codes ====================
    {
        int k  = blockIdx.x * 4 + (tid >> 6);
        int ll = tid & 63;
        if (ll == 0) cnt[k] = 0;
        sum_new[(size_t)k * D_ + ll]      = 0.0f;
        sum_new[(size_t)k * D_ + 64 + ll] = 0.0f;
        float a  = emb[(size_t)k * D_ + ll];
        float b2 = emb[(size_t)k * D_ + 64 + ll];
        f16 ah = (f16)a;  f16 al = (f16)(a - (float)ah);
        f16 bh = (f16)b2; f16 bl = (f16)(b2 - (float)bh);
        eh[(size_t)k * D_ + ll]      = ah;
        eh[(size_t)k * D_ + 64 + ll] = bh;
        el[(size_t)k * D_ + ll]      = al;
        el[(size_t)k * D_ + 64 + ll] = bl;
        float s = a * a + b2 * b2;
#pragma unroll
        for (int off = 32; off > 0; off >>= 1) s += __shfl_down(s, off, 64);
        if (ll == 0) hn[k] = 0.5f * s;
    }

    // ================= PROLOGUE: padded transpose, 2 phases =================
    float (*tile)[129] = (float(*)[129])&BS[0][0][0];   // 33 KB of the 64 KB
    f16x8 azh[4][4], azl[4][4];
#pragma unroll
    for (int ph2 = 0; ph2 < 2; ph2++) {
        const float* zb = zbase + ph2 * 64;
#pragma unroll
        for (int it = 0; it < 8; it++) {
            int flat = it * 256 + tid;       // 128 d x 16 qq
            int d  = flat >> 4;
            int qq = flat & 15;
            float4 zv = *(const float4*)(zb + (size_t)d * T_ + qq * 4);
            tile[qq * 4 + 0][d] = zv.x;
            tile[qq * 4 + 1][d] = zv.y;
            tile[qq * 4 + 2][d] = zv.z;
            tile[qq * 4 + 3][d] = zv.w;
        }
        __syncthreads();

        // A fragments for the waves owning this row-half (wave-uniform branch)
        if (wm == ph2) {
#pragma unroll
            for (int mi = 0; mi < 4; mi++) {
                int ml = mi * 16 + c15;
#pragma unroll
                for (int s = 0; s < 4; s++) {
                    int d0 = s * 32 + q * 8;
                    f16x8 hv, lv;
#pragma unroll
                    for (int j = 0; j < 8; j++) {
                        float v = tile[ml][d0 + j];
                        f16 h = (f16)v;
                        hv[j] = h; lv[j] = (f16)(v - (float)h);
                    }
                    azh[mi][s] = hv; azl[mi][s] = lv;
                }
            }
        }

        // zt rows (fp32 transposed copy for segsum): coalesced float4 stores
#pragma unroll
        for (int it = 0; it < 8; it++) {
            int flat = it * 256 + tid;
            int tl = flat >> 5;
            int d4 = (flat & 31) * 4;
            float4 v = {tile[tl][d4], tile[tl][d4 + 1],
                        tile[tl][d4 + 2], tile[tl][d4 + 3]};
            *(float4*)&zt[(size_t)(n0 + ph2 * 64 + tl) * D_ + d4] = v;
        }
        __syncthreads();                 // tile consumed; safe to reuse
    }

    // ---- grid-wide: eh/el/hn/cnt now visible (software barrier) -----------
    grid_barrier(&bars[0], GRID_A);

    // ---- hn(tile0) -> regs ----
    float hc0 = hn[wn * 32 + c15];
    float hc1 = hn[wn * 32 + 16 + c15];

    // ================= B tile-0 stage (proven structure) ====================
    int soff[4];
#pragma unroll
    for (int i = 0; i < 4; i++) {
        int row = w * 16 + i * 4 + q;
        int g   = c15 ^ (row & 15);
        soff[i] = row * 256 + g * 16;
    }
    const char* ep = (const char*)eh;
    const char* lp = (const char*)el;
#pragma unroll
    for (int i = 0; i < 4; i++) {
        load_lds16(ep + soff[i], &BS[0][0][(w * 16 + i * 4) * 128]);
        load_lds16(lp + soff[i], &BS[0][1][(w * 16 + i * 4) * 128]);
    }
    ep += 16384; lp += 16384;            // -> tile 1

    float maxv[4][4];
    int   maxk[4][4];
#pragma unroll
    for (int mi = 0; mi < 4; mi++)
#pragma unroll
        for (int r = 0; r < 4; r++) { maxv[mi][r] = -FLT_MAX; maxk[mi][r] = 0x7fffffff; }

    // ================= MAIN LOOP (unchanged) ================================
    for (int t = 0; t < 32; t++) {
        const int cur = t & 1;
        float hp0 = 0.0f, hp1 = 0.0f;
        if (t < 31) {
            // hn prefetch FIRST (older than the stage loads -> covered by vmcnt(8))
            hp0 = hn[(t + 1) * 64 + wn * 32 + c15];
            hp1 = hn[(t + 1) * 64 + wn * 32 + 16 + c15];
#pragma unroll
            for (int i = 0; i < 4; i++) {
                load_lds16(ep + soff[i], &BS[cur ^ 1][0][(w * 16 + i * 4) * 128]);
                load_lds16(lp + soff[i], &BS[cur ^ 1][1][(w * 16 + i * 4) * 128]);
            }
            ep += 16384; lp += 16384;
            asm volatile("s_waitcnt vmcnt(8)" ::: "memory");
        } else {
            asm volatile("s_waitcnt vmcnt(0)" ::: "memory");
        }
        __builtin_amdgcn_s_barrier();
        asm volatile("" ::: "memory");   // keep ds_reads below the barrier

        // acc init = -h  (dist = h - dot;  argmin(dist) == argmax(dot - h))
        f32x4 acc[4][2];
#pragma unroll
        for (int mi = 0; mi < 4; mi++) {
            acc[mi][0] = (f32x4){-hc0, -hc0, -hc0, -hc0};
            acc[mi][1] = (f32x4){-hc1, -hc1, -hc1, -hc1};
        }

        const f16* __restrict__ BH = &BS[cur][0][0];
        const f16* __restrict__ BL = &BS[cur][1][0];
#pragma unroll
        for (int s = 0; s < 4; s++) {
            const int gp = (s * 4 + q) ^ c15;
            f16x8 bh[2], bl[2];
#pragma unroll
            for (int ni = 0; ni < 2; ni++) {
                int n = wn * 32 + ni * 16 + c15;
                bh[ni] = *(const f16x8*)&BH[n * 128 + gp * 8];
                bl[ni] = *(const f16x8*)&BL[n * 128 + gp * 8];
            }
            __builtin_amdgcn_s_setprio(1);
#pragma unroll
            for (int mi = 0; mi < 4; mi++)
#pragma unroll
                for (int ni = 0; ni < 2; ni++) {
                    acc[mi][ni] = __builtin_amdgcn_mfma_f32_16x16x32_f16(
                        azh[mi][s], bh[ni], acc[mi][ni], 0, 0, 0);
                    acc[mi][ni] = __builtin_amdgcn_mfma_f32_16x16x32_f16(
                        azl[mi][s], bh[ni], acc[mi][ni], 0, 0, 0);
                    acc[mi][ni] = __builtin_amdgcn_mfma_f32_16x16x32_f16(
                        azh[mi][s], bl[ni], acc[mi][ni], 0, 0, 0);
                }
            __builtin_amdgcn_s_setprio(0);
        }

        // ---- running argmax (codes ascend: t, ni ascending; strict >) ----
        const int k0 = t * 64;
#pragma unroll
        for (int ni = 0; ni < 2; ni++) {
            int k = k0 + wn * 32 + ni * 16 + c15;
#pragma unroll
            for (int mi = 0; mi < 4; mi++)
#pragma unroll
                for (int r = 0; r < 4; r++) {
                    float v = acc[mi][ni][r];
                    if (v > maxv[mi][r]) { maxv[mi][r] = v; maxk[mi][r] = k; }
                }
        }
        hc0 = hp0; hc1 = hp1;

        asm volatile("" ::: "memory");   // keep ds_reads above this barrier
        __builtin_amdgcn_s_barrier();    // buf[cur] free for overwrite next iter
    }

    // ================= EPILOGUE 1: argmax reduce -> idx/pos/cnt =============
    __syncthreads();                     // all MFMA/LDS reads done; alias BS
    float* redv  = (float*)&BS[0][0][0];             // [128][2]
    int*   redi  = (int*)&BS[0][1][0];
    int*   scode = (int*)((char*)&BS[0][0][0] + 49152);   // 128 ints
#pragma unroll
    for (int mi = 0; mi < 4; mi++)
#pragma unroll
        for (int r = 0; r < 4; r++) {
            float bv = maxv[mi][r];
            int   bi = maxk[mi][r];
#pragma unroll
            for (int msk = 1; msk < 16; msk <<= 1) {
                float ov = __shfl_xor(bv, msk, 64);
                int   oi = __shfl_xor(bi, msk, 64);
                if (ov > bv || (ov == bv && oi < bi)) { bv = ov; bi = oi; }
            }
            if (c15 == 0) {
                int row = wm * 64 + mi * 16 + q * 4 + r;
                redv[row * 2 + wn] = bv;
                redi[row * 2 + wn] = bi;
            }
        }
    __syncthreads();
    if (tid < 128) {
        float v0 = redv[tid * 2 + 0]; int i0 = redi[tid * 2 + 0];
        float v1 = redv[tid * 2 + 1]; int i1 = redi[tid * 2 + 1];
        if (v1 > v0 || (v1 == v0 && i1 < i0)) { v0 = v1; i0 = i1; }
        int n = n0 + tid;
        idx[n] = i0;
        pos[n] = atomicAdd(&cnt[i0], 1);     // fused assign_kernel
        scode[tid] = i0;
    }

    // ================= EPILOGUE 2: fused STE (two 64-row phases) ============
    float (*etile)[129] = (float(*)[129])&BS[0][0][0];     // 33 KB
    float lsum = 0.0f;
#pragma unroll 1
    for (int ph = 0; ph < 2; ph++) {
        __syncthreads();                 // redv/redi consumed / prev phase done
#pragma unroll
        for (int pass = 0; pass < 8; pass++) {
            int row = pass * 8 + (tid >> 5);
            int dd  = (tid & 31) * 4;
            float4 ev = *(const float4*)(emb + (size_t)scode[ph * 64 + row] * D_ + dd);
            etile[row][dd + 0] = ev.x;
            etile[row][dd + 1] = ev.y;
            etile[row][dd + 2] = ev.z;
            etile[row][dd + 3] = ev.w;
        }
        __syncthreads();
        const float* zb2 = zbase + ph * 64;
        float*       ob2 = obase + ph * 64;
#pragma unroll
        for (int it = 0; it < 8; it++) {
            int flat = it * 256 + tid;
            int d  = flat >> 4;
            int qq = flat & 15;
            float4 zv = *(const float4*)(zb2 + (size_t)d * T_ + qq * 4);
            float zi[4] = {zv.x, zv.y, zv.z, zv.w};
            float ov[4];
#pragma unroll
            for (int j = 0; j < 4; j++) {
                float e  = etile[qq * 4 + j][d];
                float df = e - zi[j];        // z_vq - zf (one rounding)
                ov[j] = zi[j] + df;          // zf + (z_vq - zf), matches reference STE
                lsum += df * df;
            }
            float4 o4 = {ov[0], ov[1], ov[2], ov[3]};
            *(float4*)(ob2 + (size_t)d * T_ + qq * 4) = o4;
        }
    }
    __syncthreads();
    float* red = (float*)((char*)&BS[0][0][0] + 40960);    // 256 floats
    red[tid] = lsum;
    __syncthreads();
    for (int s = 128; s > 0; s >>= 1) {
        if (tid < s) red[tid] += red[tid + s];
        __syncthreads();
    }
    if (tid == 0) atomicAdd(s_loss, red[0]);

    // ================= EPILOGUE 3: ticket'd exclusive scan ==================
    __syncthreads();
    int* part = (int*)((char*)&BS[0][0][0] + 53248);       // 256 ints
    int* flag = (int*)((char*)&BS[0][0][0] + 57344);
    if (tid == 0) {
        __threadfence();
        int tk = __hip_atomic_fetch_add(ticket, 1, __ATOMIC_ACQ_REL,
                                        __HIP_MEMORY_SCOPE_AGENT);
        flag[0] = (tk == GRID_A - 1) ? 1 : 0;
    }
    __syncthreads();
    if (flag[0]) {                       // block-uniform branch
        int loc[8];
        int s = 0;
#pragma unroll
        for (int j = 0; j < 8; j++) {
            int c = __hip_atomic_load(&cnt[tid * 8 + j], __ATOMIC_RELAXED,
                                      __HIP_MEMORY_SCOPE_AGENT);
            loc[j] = s; s += c;
        }
        part[tid] = s;
        __syncthreads();
        for (int off = 1; off < 256; off <<= 1) {
            int v = (tid >= off) ? part[tid - off] : 0;
            __syncthreads();
            part[tid] += v;
            __syncthreads();
        }
        int pre = (tid == 0) ? 0 : part[tid - 1];
#pragma unroll
        for (int j = 0; j < 8; j++) offs[tid * 8 + j] = pre + loc[j];
        if (tid == 255) offs[2048] = pre + s;    // == N
    }
}

// ---------------------------------------------------------------------------
// TAIL: bucket -> barrier -> segsum -> barrier -> update -> ticket finalize.
// Plain launch + software grid barriers (512 small blocks, fully resident).
// Phase bodies byte-identical to R8's passing kernels.
// ---------------------------------------------------------------------------
__global__ __launch_bounds__(256)
void tail_kernel(const float* __restrict__ zt, const int* __restrict__ idx,
                 const int* __restrict__ pos, const int* __restrict__ offs,
                 int* __restrict__ row_list,
                 const float* __restrict__ emb, const float* __restrict__ emb_sum,
                 const float* __restrict__ emb_elem, const float* __restrict__ emb_rand,
                 float* __restrict__ sum_new,
                 float* __restrict__ out_emb_new, float* __restrict__ out_emb_sum_n,
                 float* __restrict__ out_emb_elem_n,
                 float* __restrict__ scalars, int* __restrict__ bars,
                 float* __restrict__ out_loss, float* __restrict__ out_ent,
                 float* __restrict__ out_dk) {
    const int tid = threadIdx.x;
    const int bid = blockIdx.x;
    __shared__ float red[256];

    // ---- phase 1: bucket (blocks 0..255 active) ----
    {
        int n = bid * 256 + tid;
        if (n < N_) row_list[offs[idx[n]] + pos[n]] = n;
    }
    grid_barrier(&bars[1], GRID_T);

    // ---- phase 2: segsum (512 blocks x 4 waves = 2048 waves, reg-preload) --
    {
        const int l    = tid & 63;
        const int wid  = bid * 4 + (tid >> 6);
        const int base = wid * 32;
        int myrow  = row_list[base + (l & 31)];
        int mycode = idx[myrow];

        float2 zb[32];
#pragma unroll
        for (int i = 0; i < 32; i++) {
            int r = __shfl(myrow, i, 64);
            zb[i] = *(const float2*)&zt[(size_t)r * D_ + l * 2];
        }
        float ax = 0.0f, ay = 0.0f;
        int curc = __shfl(mycode, 0, 64);
#pragma unroll
        for (int i = 0; i < 32; i++) {
            int c = __shfl(mycode, i, 64);
            if (c != curc) {             // wave-uniform branch
                atomicAdd(&sum_new[(size_t)curc * D_ + l * 2],     ax);
                atomicAdd(&sum_new[(size_t)curc * D_ + l * 2 + 1], ay);
                ax = 0.0f; ay = 0.0f; curc = c;
            }
            ax += zb[i].x;
            ay += zb[i].y;
        }
        atomicAdd(&sum_new[(size_t)curc * D_ + l * 2],     ax);
        atomicAdd(&sum_new[(size_t)curc * D_ + l * 2 + 1], ay);
    }
    grid_barrier(&bars[2], GRID_T);

    // ---- phase 3: update (2 gids/thread; block covers 4 codes) ----
    {
        const float MU  = 0.99f;
        const float OMM = (float)(1.0 - 0.99);   // match JAX fp64 1.0-0.99 -> fp32
        float dks = 0.0f, entc = 0.0f;
#pragma unroll
        for (int half = 0; half < 2; half++) {
            int gid = bid * 512 + half * 256 + tid;
            int k = gid >> 7;
            int d = gid & 127;
            float sn = sum_new[gid];
            float es = emb_sum[gid];
            float en = (float)(offs[k + 1] - offs[k]);
            float ee = emb_elem[k];
            float esn = MU * es + OMM * sn;
            float een = MU * ee + OMM * en;
            out_emb_sum_n[gid] = esn;
            float enew = (een >= 1.0f) ? (esn / een) : emb_rand[gid];
            out_emb_new[gid] = enew;
            if (d == 0) {
                out_emb_elem_n[k] = een;
                float p = en * (1.0f / 65536.0f);   // sum(elem_new) == N in fp32
                entc += p * logf(p + 1e-8f);
            }
            float df = enew - emb[gid];
            dks += df * df;
        }
        red[tid] = dks;
        __syncthreads();
        for (int s = 128; s > 0; s >>= 1) {
            if (tid < s) red[tid] += red[tid + s];
            __syncthreads();
        }
        float dkv = red[0];
        __syncthreads();
        red[tid] = entc;
        __syncthreads();
        for (int s = 128; s > 0; s >>= 1) {
            if (tid < s) red[tid] += red[tid + s];
            __syncthreads();
        }
        if (tid == 0) {
            atomicAdd(&scalars[2], dkv);     // s_dk
            atomicAdd(&scalars[1], red[0]);  // s_ent
            __threadfence();
            int t = __hip_atomic_fetch_add(&bars[3], 1, __ATOMIC_ACQ_REL,
                                           __HIP_MEMORY_SCOPE_AGENT);
            if (t == GRID_T - 1) {           // last block: finalize scalars
                float lossv = __hip_atomic_load(&scalars[0], __ATOMIC_RELAXED,
                                                __HIP_MEMORY_SCOPE_AGENT);
                float entv  = __hip_atomic_load(&scalars[1], __ATOMIC_RELAXED,
                                                __HIP_MEMORY_SCOPE_AGENT);
                float dkss  = __hip_atomic_load(&scalars[2], __ATOMIC_RELAXED,
                                                __HIP_MEMORY_SCOPE_AGENT);
                out_loss[0] = lossv;
                out_ent[0]  = expf(-entv);
                out_dk[0]   = sqrtf(dkss) * (1.0f / 512.0f);   // sqrt(K*D) = 512
            }
        }
    }
}

// ---------------------------------------------------------------------------
extern "C" void kernel_launch(void* const* d_in, const int* in_sizes, int n_in,
                              void* d_out, int out_size, void* d_ws, size_t ws_size,
                              hipStream_t stream) {
    (void)in_sizes; (void)n_in; (void)out_size; (void)ws_size;

    const float* z        = (const float*)d_in[0];   // [32,128,2048]
    const float* emb      = (const float*)d_in[1];   // [2048,128]
    const float* emb_sum  = (const float*)d_in[2];   // [2048,128]
    const float* emb_elem = (const float*)d_in[3];   // [2048]
    const float* emb_rand = (const float*)d_in[4];   // [2048,128]

    float* out = (float*)d_out;
    float* out0            = out;                            // z_vq_out  8388608
    float* out_loss        = out + 8388608;                  // scalar
    float* out_emb_new     = out + 8388609;                  // 262144
    float* out_emb_sum_n   = out + 8388609 + 262144;         // 262144
    float* out_emb_elem_n  = out + 8388609 + 524288;         // 2048
    float* out_ent         = out + 8388609 + 524288 + 2048;  // scalar
    float* out_dk          = out_ent + 1;                    // scalar

    float* ws = (float*)d_ws;                     // offsets in floats
    float* zt       = ws;                         // 8388608 f (fp32 z^T [N][D])
    int*   idx      = (int*)(ws + 8388608);       // 65536
    float* hn       = ws + 8454144;               // 2048
    f16*   eh       = (f16*)(ws + 8456192);       // 262144 halves (131072 f)
    f16*   el       = (f16*)(ws + 8587264);       // 262144 halves
    float* sum_new  = ws + 8718336;               // 262144
    int*   cnt      = (int*)(ws + 8980480);       // 2048
    float* scalars  = ws + 8982528;               // [0] loss [1] ent [2] dk
    float* s_loss   = scalars;
    int*   tickA    = (int*)(scalars + 3);        // argmin scan ticket
    int*   bars     = (int*)(scalars + 4);        // [0] barA [1] barT1 [2] barT2 [3] tickU
    int*   pos      = (int*)(ws + 8982536);       // 65536
    int*   offs     = (int*)(ws + 9048072);       // 2049
    int*   row_list = (int*)(ws + 9050121);       // 65536
                                                  // end 9115657 f ~ 36.5 MB

    // zero scalars + tickets + barrier counters (graph-capture-safe)
    hipMemsetAsync(scalars, 0, 8 * sizeof(float), stream);

    argmin_mfma<<<GRID_A, 256, 0, stream>>>(z, eh, el, hn, emb, zt, out0,
                                            idx, cnt, pos, offs, tickA,
                                            s_loss, scalars, sum_new, bars);
    tail_kernel<<<GRID_T, 256, 0, stream>>>(zt, idx, pos, offs, row_list,
                                            emb, emb_sum, emb_elem, emb_rand,
                                            sum_new, out_emb_new, out_emb_sum_n,
                                            out_emb_elem_n, scalars, bars,
                                            out_loss, out_ent, out_dk);
}